// Round 5
// baseline (2558.700 us; speedup 1.0000x reference)
//
#include <hip/hip_runtime.h>

// CRF forward on MI355X — R4: R3's MFMA scan + LDS-only barrier + distance-2 prefetch.
// Steady-state cross-wave traffic is exclusively LDS, so the per-step barrier is a raw
// "s_waitcnt lgkmcnt(0); s_barrier" — global y/mask prefetches are never drained at the
// barrier (the compiler's __syncthreads emits vmcnt(0), which exposed ~900 cyc HBM
// latency per step in R3). Prefetch distance 2 covers HBM latency with ~2 steps of work.

typedef _Float16 h8 __attribute__((ext_vector_type(8)));
typedef _Float16 h4 __attribute__((ext_vector_type(4)));
typedef float    f4 __attribute__((ext_vector_type(4)));

#define TT 2048
#define KK 256
#define NB 16          // batches per block (MFMA N)
#define SOS_IDX 2
#define VSTR 264       // fp16 elems per V row: 256 + 8 pad

#define MFMA16(a, b, c) __builtin_amdgcn_mfma_f32_16x16x32_f16((a), (b), (c), 0, 0, 0)

// Workgroup barrier that drains ONLY LDS ops (cross-wave comm is LDS-only here).
__device__ __forceinline__ void barrier_lds_only() {
    asm volatile("s_waitcnt lgkmcnt(0)\n\ts_barrier" ::: "memory");
}

__global__ __launch_bounds__(256, 1)
void crf_fwd_kernel(const float* __restrict__ y, const float* __restrict__ mask,
                    const float* __restrict__ trans, float* __restrict__ out) {
    const int bi   = blockIdx.x;
    const int b0   = bi * NB;
    const int tid  = threadIdx.x;
    const int w    = tid >> 6;     // wave 0..3 -> state tiles 4w..4w+3
    const int lane = tid & 63;
    const int bl   = lane & 15;    // batch column (MFMA N index)
    const int g    = lane >> 4;    // quad (MFMA K/M group)

    __shared__ _Float16 Vb[2][NB][VSTR];   // double-buffered V, [batch][state]
    __shared__ _Float16 CEh[KK];

    // ---- CE[j] = sum_k exp(trans[k][j])
    float ce = 0.f;
    for (int k = 0; k < KK; ++k) ce += __expf(trans[(size_t)k * KK + tid]);

    // ---- zero V[0]; publish CE
    for (int idx = tid; idx < NB * VSTR; idx += 256) (&Vb[0][0][0])[idx] = (_Float16)0.f;
    CEh[tid] = (_Float16)ce;
    __syncthreads();
    if (tid < NB) Vb[0][tid][SOS_IDX] = (_Float16)1.f;   // V0 = one-hot(SOS)

    // ---- E fragments (A-operand): ea[i][kt] for rows m=(4w+i)*16+bl
    h8 ea[4][8];
    #pragma unroll
    for (int i = 0; i < 4; ++i) {
        const int m = (w * 4 + i) * 16 + bl;
        const float* tr = trans + (size_t)m * KK;
        #pragma unroll
        for (int kt = 0; kt < 8; ++kt) {
            const int k0 = kt * 32 + g * 8;
            float4 v0 = *(const float4*)(tr + k0);
            float4 v1 = *(const float4*)(tr + k0 + 4);
            h8 a;
            a[0] = (_Float16)__expf(v0.x); a[1] = (_Float16)__expf(v0.y);
            a[2] = (_Float16)__expf(v0.z); a[3] = (_Float16)__expf(v0.w);
            a[4] = (_Float16)__expf(v1.x); a[5] = (_Float16)__expf(v1.y);
            a[6] = (_Float16)__expf(v1.z); a[7] = (_Float16)__expf(v1.w);
            ea[i][kt] = a;
        }
    }
    __syncthreads();   // one-hot + CEh visible

    // ---- T-tile A fragment: all rows = CE  ->  every lane's acc = T_b
    h8 at[8];
    #pragma unroll
    for (int kt = 0; kt < 8; ++kt) at[kt] = *(const h8*)&CEh[kt * 32 + g * 8];

    // ---- per-lane kept V slices for masked steps
    h4 keep[4];
    #pragma unroll
    for (int i = 0; i < 4; ++i) {
        const int k0w = (w * 4 + i) * 16 + g * 4;
        h4 kv;
        #pragma unroll
        for (int r = 0; r < 4; ++r) kv[r] = (_Float16)((k0w + r == SOS_IDX) ? 1.f : 0.f);
        keep[i] = kv;
    }

    // ---- distance-2 software pipeline for y and mask
    const float* ybase = y + (size_t)(b0 + bl) * TT * KK;
    const float* mbase = mask + (size_t)(b0 + bl) * TT;
    float4 yv0[4], yv1[4];
    #pragma unroll
    for (int i = 0; i < 4; ++i) yv0[i] = *(const float4*)(ybase + (w * 4 + i) * 16 + g * 4);
    float mv0 = mbase[0];
    #pragma unroll
    for (int i = 0; i < 4; ++i) yv1[i] = *(const float4*)(ybase + (size_t)KK + (w * 4 + i) * 16 + g * 4);
    float mv1 = mbase[1];

    float Lam = 0.f;
    int cur = 0;

    for (int t = 0; t < TT; ++t) {
        // emissions for THIS step (from load issued 2 steps ago)
        float eyv[4][4];
        #pragma unroll
        for (int i = 0; i < 4; ++i) {
            eyv[i][0] = __expf(yv0[i].x); eyv[i][1] = __expf(yv0[i].y);
            eyv[i][2] = __expf(yv0[i].z); eyv[i][3] = __expf(yv0[i].w);
        }
        const bool msk = (mv0 > 0.5f);

        // issue prefetch for t+2 (stays in flight across the LDS-only barrier)
        const int tn = (t + 2 < TT) ? t + 2 : TT - 1;
        float4 yn[4];
        #pragma unroll
        for (int i = 0; i < 4; ++i)
            yn[i] = *(const float4*)(ybase + (size_t)tn * KK + (w * 4 + i) * 16 + g * 4);
        float mn = mbase[tn];

        // W = E·V, T = CE·V via MFMA
        f4 acc0 = {0.f, 0.f, 0.f, 0.f}, acc1 = acc0, acc2 = acc0, acc3 = acc0, tac = acc0;
        const _Float16* Vc = &Vb[cur][0][0] + bl * VSTR + g * 8;
        #pragma unroll
        for (int kt = 0; kt < 8; ++kt) {
            h8 bf = *(const h8*)(Vc + kt * 32);   // B-frag: n=bl, k=kt*32+g*8+j
            acc0 = MFMA16(ea[0][kt], bf, acc0);
            acc1 = MFMA16(ea[1][kt], bf, acc1);
            acc2 = MFMA16(ea[2][kt], bf, acc2);
            acc3 = MFMA16(ea[3][kt], bf, acc3);
            tac  = MFMA16(at[kt],    bf, tac);
        }

        // normalize, apply emissions, masked select, store
        const float Tb  = tac[0];
        const float inv = __builtin_amdgcn_rcpf(Tb);

        f4 accs[4] = {acc0, acc1, acc2, acc3};
        #pragma unroll
        for (int i = 0; i < 4; ++i) {
            h4 nv;
            #pragma unroll
            for (int r = 0; r < 4; ++r) nv[r] = (_Float16)(accs[i][r] * eyv[i][r] * inv);
            h4 sv = msk ? nv : keep[i];
            keep[i] = sv;
            const int k0w = (w * 4 + i) * 16 + g * 4;
            *(h4*)(&Vb[cur ^ 1][bl][k0w]) = sv;
        }
        Lam += msk ? __logf(Tb) : 0.f;

        // rotate pipeline
        #pragma unroll
        for (int i = 0; i < 4; ++i) { yv0[i] = yv1[i]; yv1[i] = yn[i]; }
        mv0 = mv1; mv1 = mn;
        cur ^= 1;
        barrier_lds_only();   // LDS-only drain: global prefetches stay in flight
    }

    // ---- final: S_b = sum_k V[k,b] via ones-A MFMA
    h8 ones8;
    #pragma unroll
    for (int j = 0; j < 8; ++j) ones8[j] = (_Float16)1.f;
    f4 sac = {0.f, 0.f, 0.f, 0.f};
    const _Float16* Vc = &Vb[cur][0][0] + bl * VSTR + g * 8;
    #pragma unroll
    for (int kt = 0; kt < 8; ++kt) {
        h8 bf = *(const h8*)(Vc + kt * 32);
        sac = MFMA16(ones8, bf, sac);
    }
    if (tid < NB) out[b0 + tid] = __logf(sac[0]) + Lam;
}

extern "C" void kernel_launch(void* const* d_in, const int* in_sizes, int n_in,
                              void* d_out, int out_size, void* d_ws, size_t ws_size,
                              hipStream_t stream) {
    const float* y     = (const float*)d_in[0];   // (B, T, K) fp32
    const float* mask  = (const float*)d_in[1];   // (B, T)    fp32
    const float* trans = (const float*)d_in[2];   // (K, K)    fp32
    float* out = (float*)d_out;                   // (B,)      fp32
    const int B = in_sizes[1] / TT;
    crf_fwd_kernel<<<B / NB, 256, 0, stream>>>(y, mask, trans, out);
}